// Round 14
// baseline (25.795 us; speedup 1.0000x reference)
//
#include <hip/hip_runtime.h>
#include <hip/hip_bf16.h>
#include <float.h>

#define EPSV 1e-6f
#define SRC_BLK 256        // srcs per block = 16 fragments x 16 cols
#define NFRAG 16
#define LT_MAX 4096        // targets staged per super-tile (64 KB LDS)
#define WAVES 8            // 512 threads

typedef float  f32x4_t  __attribute__((ext_vector_type(4)));
typedef short  bf16x8_t __attribute__((ext_vector_type(8)));
typedef unsigned short u16;
typedef u16    u16x8    __attribute__((ext_vector_type(8)));

__device__ __forceinline__ u16 bf_hi(float v) {
    return __bfloat16_as_ushort(__float2bfloat16(v));   // RNE
}
__device__ __forceinline__ float bf_f(u16 u) {
    return __bfloat162float(__ushort_as_bfloat16(u));
}

// Single-kernel directed Hausdorff via MFMA. Per (dir,b,src-block of 256):
//   dot(A_row(tgt), B_col(src)) = t2 - 2 s'.t   (K=8 bf16 hi/lo slots)
//   A (targets, rows): [txh, txl, txh, tyh, tyl, tyh, t2h, t2l]
//   B (srcs, cols):    [-2sxh, -2sxh, -2sxl, -2syh, -2syh, -2syl, 1, 1]
// D = A.B via mfma_f32_16x16x32_bf16: lane holds col(src)=lane&15, 4 tgt rows
// -> 2 min3 per MFMA; per-src min across row-groups via shfl_xor(16,32).
// B-side k>=8 lanes are ZERO (zslot) so A-side k>=8 garbage contributes 0.
// EPILOGUE FUSION (replaces the finalize kernel): sqrt is monotone and
// res[b]>0, so max over blocks of sqrt(v_blk)*res[b] == sqrt(max v)*res[b].
// Each block does ONE atomicMax(float) on out[b]. fmax is idempotent ->
// deterministic across graph replays (out's 0xAA poison = tiny NEGATIVE
// float, recovered by fmax; correctness call starts from memset-0).
__global__ __launch_bounds__(512, 1) void hausdorff_mfma_kernel(
    const float* __restrict__ c1, const float* __restrict__ c2,
    const float* __restrict__ res, float* __restrict__ out,
    int L1, int L2) {

    const int b   = blockIdx.y;
    const int dir = blockIdx.z;
    const int st  = blockIdx.x;

    const float* src; const float* tgt; int Lsrc, Ltgt;
    if (dir == 0) { src = c2 + (size_t)b * L2 * 2; tgt = c1 + (size_t)b * L1 * 2; Lsrc = L2; Ltgt = L1; }
    else          { src = c1 + (size_t)b * L1 * 2; tgt = c2 + (size_t)b * L2 * 2; Lsrc = L1; Ltgt = L2; }

    const int srcBase = st * SRC_BLK;
    if (srcBase >= Lsrc) return;   // contributes nothing

    const int lane = threadIdx.x & 63;
    const int w    = threadIdx.x >> 6;

    __shared__ u16x8 Tform[LT_MAX];           // 64 KB
    __shared__ u16x8 Sform[SRC_BLK];          // 4 KB
    __shared__ u16x8 zslot;                   // 16 B of zeros
    __shared__ float s2s[SRC_BLK];            // 1 KB
    __shared__ float red[WAVES][SRC_BLK];     // 8 KB
    __shared__ float rmax[4];

    // ---- stage S-form (threads 0..255) + zslot ----
    if (threadIdx.x < SRC_BLK) {
        const int j = srcBase + threadIdx.x;
        float sx = 0.f, sy = 0.f;
        const bool ok = (j < Lsrc);
        if (ok) {
            float2 p = ((const float2*)src)[j];
            sx = p.x + EPSV; sy = p.y + EPSV;
        }
        const float nx = -2.0f * sx, ny = -2.0f * sy;
        const u16 nxh = bf_hi(nx); const u16 nxl = bf_hi(nx - bf_f(nxh));
        const u16 nyh = bf_hi(ny); const u16 nyl = bf_hi(ny - bf_f(nyh));
        const u16 one = bf_hi(1.0f);
        u16x8 r;
        r[0] = nxh; r[1] = nxh; r[2] = nxl;
        r[3] = nyh; r[4] = nyh; r[5] = nyl;
        r[6] = one; r[7] = one;
        Sform[threadIdx.x] = r;
        s2s[threadIdx.x] = ok ? fmaf(sx, sx, sy * sy) : -FLT_MAX;
    }
    if (threadIdx.x == 256) {
        zslot = (u16x8){0, 0, 0, 0, 0, 0, 0, 0};
    }
    __syncthreads();

    // ---- load this wave's 16 src fragments (kept in registers) ----
    bf16x8_t bfrag[NFRAG];
    #pragma unroll
    for (int f = 0; f < NFRAG; ++f) {
        const bf16x8_t* bp = (lane < 16)
            ? &((const bf16x8_t*)Sform)[f * 16 + lane]
            : (const bf16x8_t*)&zslot;
        bfrag[f] = *bp;
    }

    float mm[NFRAG];
    #pragma unroll
    for (int f = 0; f < NFRAG; ++f) mm[f] = FLT_MAX;

    const f32x4_t zacc = {0.f, 0.f, 0.f, 0.f};
    const u16 padhi = bf_hi(1e30f);

    // ---- target super-tiles ----
    for (int tbase = 0; tbase < Ltgt; tbase += LT_MAX) {
        const int chunk  = min(LT_MAX, Ltgt - tbase);
        const int padded = (chunk + 15) & ~15;

        for (int e = threadIdx.x; e < padded; e += 512) {
            u16x8 r;
            if (e < chunk) {
                float2 p = ((const float2*)tgt)[tbase + e];
                const float t2 = fmaf(p.y, p.y, p.x * p.x);
                const u16 txh = bf_hi(p.x); const u16 txl = bf_hi(p.x - bf_f(txh));
                const u16 tyh = bf_hi(p.y); const u16 tyl = bf_hi(p.y - bf_f(tyh));
                const u16 t2h = bf_hi(t2);  const u16 t2l = bf_hi(t2 - bf_f(t2h));
                r[0] = txh; r[1] = txl; r[2] = txh;
                r[3] = tyh; r[4] = tyl; r[5] = tyh;
                r[6] = t2h; r[7] = t2l;
            } else {
                r = (u16x8){0, 0, 0, 0, 0, 0, 0, 0};
                r[6] = padhi;                 // dot = 1e30 -> never the min
            }
            Tform[e] = r;
        }
        __syncthreads();

        const int ntile = padded >> 4;
        const int tbeg  = (w * ntile) >> 3;
        const int tend  = ((w + 1) * ntile) >> 3;

        if (tbeg < tend) {
            const bf16x8_t* Ap = (const bf16x8_t*)Tform;
            bf16x8_t af = Ap[tbeg * 16 + (lane & 15)];
            for (int t = tbeg; t < tend; ++t) {
                const int tn = (t + 1 < tend) ? t + 1 : t;
                bf16x8_t afn = Ap[tn * 16 + (lane & 15)];   // depth-1 prefetch
                #pragma unroll
                for (int f = 0; f < NFRAG; ++f) {
                    f32x4_t acc = __builtin_amdgcn_mfma_f32_16x16x32_bf16(
                        af, bfrag[f], zacc, 0, 0, 0);
                    mm[f] = fminf(fminf(mm[f], acc[0]), acc[1]);  // v_min3
                    mm[f] = fminf(fminf(mm[f], acc[2]), acc[3]);
                }
                af = afn;
            }
        }
        __syncthreads();   // before next super-tile overwrites Tform
    }

    // ---- per-src min across the 4 row-groups, publish per wave ----
    #pragma unroll
    for (int f = 0; f < NFRAG; ++f) {
        float v = mm[f];
        v = fminf(v, __shfl_xor(v, 16));
        v = fminf(v, __shfl_xor(v, 32));
        if (lane < 16) red[w][f * 16 + lane] = v;
    }
    __syncthreads();

    // ---- combine waves, add s2, block max, fused sqrt*res + atomicMax ----
    const int t = threadIdx.x;
    float v = 0.f;
    if (t < SRC_BLK) {
        float m = red[0][t];
        #pragma unroll
        for (int ww = 1; ww < WAVES; ++ww) m = fminf(m, red[ww][t]);
        v = fmaxf(s2s[t] + m, 0.f);
    }
    for (int off = 32; off > 0; off >>= 1)
        v = fmaxf(v, __shfl_down(v, off));
    if (t < 256 && lane == 0) rmax[t >> 6] = v;
    __syncthreads();
    if (t == 0) {
        float blkmax = fmaxf(fmaxf(rmax[0], rmax[1]), fmaxf(rmax[2], rmax[3]));
        atomicMax(&out[b], sqrtf(blkmax) * res[b]);
    }
}

extern "C" void kernel_launch(void* const* d_in, const int* in_sizes, int n_in,
                              void* d_out, int out_size, void* d_ws, size_t ws_size,
                              hipStream_t stream) {
    const float* c1  = (const float*)d_in[0];
    const float* c2  = (const float*)d_in[1];
    const float* res = (const float*)d_in[2];
    float* out = (float*)d_out;

    const int B  = in_sizes[2];
    const int L1 = in_sizes[0] / (B * 2);
    const int L2 = in_sizes[1] / (B * 2);

    const int Lmax  = max(L1, L2);
    const int STmax = (Lmax + SRC_BLK - 1) / SRC_BLK;

    dim3 grid(STmax, B, 2);
    hipLaunchKernelGGL(hausdorff_mfma_kernel, grid, dim3(512), 0, stream,
                       c1, c2, res, out, L1, L2);
}

// Round 15
// 17.627 us; speedup vs baseline: 1.4634x; 1.4634x over previous
//
#include <hip/hip_runtime.h>
#include <hip/hip_bf16.h>
#include <float.h>

#define EPSV 1e-6f
#define SRC_BLK 256        // srcs per block = 8 fragments x 32 cols
#define NFRAG 8
#define LT_MAX 4096        // targets staged per super-tile (64 KB LDS)
#define WAVES 8            // 512 threads

typedef float  f32x16_t __attribute__((ext_vector_type(16)));
typedef short  bf16x8_t __attribute__((ext_vector_type(8)));
typedef unsigned short u16;
typedef u16    u16x8    __attribute__((ext_vector_type(8)));

__device__ __forceinline__ u16 bf_hi(float v) {
    return __bfloat16_as_ushort(__float2bfloat16(v));   // RNE
}
__device__ __forceinline__ float bf_f(u16 u) {
    return __bfloat162float(__ushort_as_bfloat16(u));
}

// Phase A: directed Hausdorff via mfma_f32_32x32x16_bf16 (1024 pair-dots per
// MFMA at ~8cyc vs 256 at ~4.85 for 16x16 -> 2.4x matrix-pipe efficiency).
//   dot(A_row(tgt), B_col(src)) = t2 - 2 s'.t   (K=8 bf16 hi/lo slots)
//   A row r=lane&31: [txh,txl,txh,tyh,tyl,tyh,t2h,t2l]; k-half=(lane>>5)
//     (k>=8 content = replicated row data, zeroed by B)
//   B col c=lane&31: [-2sxh,-2sxh,-2sxl,-2syh,-2syh,-2syl,1,1]; lanes>=32 ZERO
// D layout (verified m74/m101): col=lane&31, row=(reg&3)+8*(reg>>2)+4*(lane>>5)
// -> per MFMA 8x min3 absorbs 16 rows; lanes c / c+32 cover complementary
// rows -> final per-src min = shfl_xor(32). Two-kernel structure (r13-proven;
// fused atomicMax regressed in r14). Plain stores, no atomics, deterministic.
__global__ __launch_bounds__(512, 1) void hausdorff_mfma_kernel(
    const float* __restrict__ c1, const float* __restrict__ c2,
    float* __restrict__ ws, int L1, int L2, int STmax) {

    const int b   = blockIdx.y;
    const int B   = gridDim.y;
    const int dir = blockIdx.z;
    const int st  = blockIdx.x;

    const float* src; const float* tgt; int Lsrc, Ltgt;
    if (dir == 0) { src = c2 + (size_t)b * L2 * 2; tgt = c1 + (size_t)b * L1 * 2; Lsrc = L2; Ltgt = L1; }
    else          { src = c1 + (size_t)b * L1 * 2; tgt = c2 + (size_t)b * L2 * 2; Lsrc = L1; Ltgt = L2; }

    const int srcBase = st * SRC_BLK;
    if (srcBase >= Lsrc) return;   // finalize never reads these ws entries

    const int lane = threadIdx.x & 63;
    const int w    = threadIdx.x >> 6;

    __shared__ u16x8 Tform[LT_MAX];           // 64 KB
    __shared__ u16x8 Sform[SRC_BLK];          // 4 KB
    __shared__ u16x8 zslot;                   // 16 B of zeros
    __shared__ float s2s[SRC_BLK];            // 1 KB
    __shared__ float red[WAVES][SRC_BLK];     // 8 KB
    __shared__ float rmax[4];

    // ---- stage S-form (threads 0..255) + zslot ----
    if (threadIdx.x < SRC_BLK) {
        const int j = srcBase + threadIdx.x;
        float sx = 0.f, sy = 0.f;
        const bool ok = (j < Lsrc);
        if (ok) {
            float2 p = ((const float2*)src)[j];
            sx = p.x + EPSV; sy = p.y + EPSV;
        }
        const float nx = -2.0f * sx, ny = -2.0f * sy;
        const u16 nxh = bf_hi(nx); const u16 nxl = bf_hi(nx - bf_f(nxh));
        const u16 nyh = bf_hi(ny); const u16 nyl = bf_hi(ny - bf_f(nyh));
        const u16 one = bf_hi(1.0f);
        u16x8 r;
        r[0] = nxh; r[1] = nxh; r[2] = nxl;
        r[3] = nyh; r[4] = nyh; r[5] = nyl;
        r[6] = one; r[7] = one;
        Sform[threadIdx.x] = r;
        s2s[threadIdx.x] = ok ? fmaf(sx, sx, sy * sy) : -FLT_MAX;
    }
    if (threadIdx.x == 256) {
        zslot = (u16x8){0, 0, 0, 0, 0, 0, 0, 0};
    }
    __syncthreads();

    // ---- this wave's 8 src fragments (col = lane&31; hi lanes = zeros) ----
    bf16x8_t bfrag[NFRAG];
    #pragma unroll
    for (int f = 0; f < NFRAG; ++f) {
        const bf16x8_t* bp = (lane < 32)
            ? &((const bf16x8_t*)Sform)[f * 32 + lane]
            : (const bf16x8_t*)&zslot;
        bfrag[f] = *bp;
    }

    float mm[NFRAG];
    #pragma unroll
    for (int f = 0; f < NFRAG; ++f) mm[f] = FLT_MAX;

    const f32x16_t zacc = {0.f,0.f,0.f,0.f, 0.f,0.f,0.f,0.f,
                           0.f,0.f,0.f,0.f, 0.f,0.f,0.f,0.f};
    const u16 padhi = bf_hi(1e30f);

    // ---- target super-tiles ----
    for (int tbase = 0; tbase < Ltgt; tbase += LT_MAX) {
        const int chunk  = min(LT_MAX, Ltgt - tbase);
        const int padded = (chunk + 31) & ~31;

        for (int e = threadIdx.x; e < padded; e += 512) {
            u16x8 r;
            if (e < chunk) {
                float2 p = ((const float2*)tgt)[tbase + e];
                const float t2 = fmaf(p.y, p.y, p.x * p.x);
                const u16 txh = bf_hi(p.x); const u16 txl = bf_hi(p.x - bf_f(txh));
                const u16 tyh = bf_hi(p.y); const u16 tyl = bf_hi(p.y - bf_f(tyh));
                const u16 t2h = bf_hi(t2);  const u16 t2l = bf_hi(t2 - bf_f(t2h));
                r[0] = txh; r[1] = txl; r[2] = txh;
                r[3] = tyh; r[4] = tyl; r[5] = tyh;
                r[6] = t2h; r[7] = t2l;
            } else {
                r = (u16x8){0, 0, 0, 0, 0, 0, 0, 0};
                r[6] = padhi;                 // dot = 1e30 -> never the min
            }
            Tform[e] = r;
        }
        __syncthreads();

        const int ntile = padded >> 5;        // 32-row tiles
        const int tbeg  = (w * ntile) >> 3;
        const int tend  = ((w + 1) * ntile) >> 3;

        if (tbeg < tend) {
            const bf16x8_t* Ap = (const bf16x8_t*)Tform;
            bf16x8_t af = Ap[tbeg * 32 + (lane & 31)];
            for (int t = tbeg; t < tend; ++t) {
                const int tn = (t + 1 < tend) ? t + 1 : t;
                bf16x8_t afn = Ap[tn * 32 + (lane & 31)];   // depth-1 prefetch
                #pragma unroll
                for (int f = 0; f < NFRAG; ++f) {
                    f32x16_t acc = __builtin_amdgcn_mfma_f32_32x32x16_bf16(
                        af, bfrag[f], zacc, 0, 0, 0);
                    mm[f] = fminf(fminf(mm[f], acc[0]),  acc[1]);   // v_min3
                    mm[f] = fminf(fminf(mm[f], acc[2]),  acc[3]);
                    mm[f] = fminf(fminf(mm[f], acc[4]),  acc[5]);
                    mm[f] = fminf(fminf(mm[f], acc[6]),  acc[7]);
                    mm[f] = fminf(fminf(mm[f], acc[8]),  acc[9]);
                    mm[f] = fminf(fminf(mm[f], acc[10]), acc[11]);
                    mm[f] = fminf(fminf(mm[f], acc[12]), acc[13]);
                    mm[f] = fminf(fminf(mm[f], acc[14]), acc[15]);
                }
                af = afn;
            }
        }
        __syncthreads();   // before next super-tile overwrites Tform
    }

    // ---- per-src min across the two k-half row sets, publish per wave ----
    #pragma unroll
    for (int f = 0; f < NFRAG; ++f) {
        float v = mm[f];
        v = fminf(v, __shfl_xor(v, 32));
        if (lane < 32) red[w][f * 32 + lane] = v;
    }
    __syncthreads();

    // ---- combine waves, add s2, block max, one plain store ----
    const int t = threadIdx.x;
    float v = 0.f;
    if (t < SRC_BLK) {
        float m = red[0][t];
        #pragma unroll
        for (int ww = 1; ww < WAVES; ++ww) m = fminf(m, red[ww][t]);
        v = fmaxf(s2s[t] + m, 0.f);
    }
    for (int off = 32; off > 0; off >>= 1)
        v = fmaxf(v, __shfl_down(v, off));
    if (t < 256 && lane == 0) rmax[t >> 6] = v;
    __syncthreads();
    if (t == 0) {
        ws[(size_t)(dir * B + b) * STmax + st] =
            fmaxf(fmaxf(rmax[0], rmax[1]), fmaxf(rmax[2], rmax[3]));
    }
}

// Phase B: per batch, max over the two directions' block maxima, sqrt, scale.
__global__ void hausdorff_finalize_kernel(
    const float* __restrict__ ws, const float* __restrict__ res,
    float* __restrict__ out, int STmax, int nst0, int nst1, int B) {

    const int b = blockIdx.x;
    const int lane = threadIdx.x;
    float v = 0.f;
    for (int i = lane; i < nst0 + nst1; i += 64) {
        v = fmaxf(v, (i < nst0) ? ws[(size_t)(0 * B + b) * STmax + i]
                                : ws[(size_t)(1 * B + b) * STmax + (i - nst0)]);
    }
    for (int off = 32; off > 0; off >>= 1)
        v = fmaxf(v, __shfl_down(v, off));
    if (lane == 0) out[b] = sqrtf(v) * res[b];
}

extern "C" void kernel_launch(void* const* d_in, const int* in_sizes, int n_in,
                              void* d_out, int out_size, void* d_ws, size_t ws_size,
                              hipStream_t stream) {
    const float* c1  = (const float*)d_in[0];
    const float* c2  = (const float*)d_in[1];
    const float* res = (const float*)d_in[2];
    float* out = (float*)d_out;

    const int B  = in_sizes[2];
    const int L1 = in_sizes[0] / (B * 2);
    const int L2 = in_sizes[1] / (B * 2);

    float* ws = (float*)d_ws;

    const int Lmax  = max(L1, L2);
    const int STmax = (Lmax + SRC_BLK - 1) / SRC_BLK;
    const int nst0  = (L2 + SRC_BLK - 1) / SRC_BLK;   // dir0: src = c2
    const int nst1  = (L1 + SRC_BLK - 1) / SRC_BLK;   // dir1: src = c1

    dim3 gridA(STmax, B, 2);
    hipLaunchKernelGGL(hausdorff_mfma_kernel, gridA, dim3(512), 0, stream,
                       c1, c2, ws, L1, L2, STmax);

    hipLaunchKernelGGL(hausdorff_finalize_kernel, dim3(B), dim3(64), 0, stream,
                       ws, res, out, STmax, nst0, nst1, B);
}